// Round 3
// baseline (584.618 us; speedup 1.0000x reference)
//
#include <hip/hip_runtime.h>
#include <hip/hip_bf16.h>

#define N_PTS 16384
#define TEMP_F 0.05f

__device__ __forceinline__ float selu_f(float x) {
    const float scale = 1.0507009873554805f;
    const float alpha = 1.6732632423543772f;
    return x > 0.f ? scale * x : scale * alpha * (__expf(x) - 1.f);
}

// ---------------------------------------------------------------------------
// Kernel A: fused 5-layer MLP, fp32.
// Block = 512 threads, 64 rows/block.  h in LDS as [k][r] (64 KB).
// Thread t: row r = t&63, column-chunk g = t>>6 (wave-uniform -> scalar W
// loads), columns [32g, 32g+32).
// ---------------------------------------------------------------------------
__global__ __launch_bounds__(512) void mlp_kernel(
    const float* __restrict__ z,
    const float* __restrict__ W1, const float* __restrict__ b1,
    const float* __restrict__ W2, const float* __restrict__ b2,
    const float* __restrict__ W3, const float* __restrict__ b3,
    const float* __restrict__ W4, const float* __restrict__ b4,
    const float* __restrict__ W5, const float* __restrict__ b5,
    float* __restrict__ gen)
{
    __shared__ float h[256 * 64];   // h[k*64 + r]

    const int t = threadIdx.x;
    const int r = t & 63;
    const int g = __builtin_amdgcn_readfirstlane(t >> 6);   // 0..7, wave-uniform
    const int c0 = g * 32;
    const int row0 = blockIdx.x * 64;

    // stage z[row0..row0+64][0..32] transposed into h[k*64+r]
    #pragma unroll
    for (int e = 0; e < 4; e++) {
        int f  = t + e * 512;        // 0..2047
        int rz = f >> 5;
        int kz = f & 31;
        h[kz * 64 + rz] = z[(row0 + rz) * 32 + kz];
    }
    __syncthreads();

    float acc[32];

    // ---- layer 1 (32 -> 256) ----
    #pragma unroll
    for (int j = 0; j < 32; j++) acc[j] = b1[c0 + j];
    for (int k = 0; k < 32; k++) {
        float hv = h[k * 64 + r];
        const float* Wr = W1 + k * 256 + c0;
        #pragma unroll
        for (int j = 0; j < 32; j++) acc[j] = fmaf(hv, Wr[j], acc[j]);
    }
    __syncthreads();
    #pragma unroll
    for (int j = 0; j < 32; j++) h[(c0 + j) * 64 + r] = selu_f(acc[j]);
    __syncthreads();

    // ---- layers 2..4 (256 -> 256) ----
    for (int layer = 0; layer < 3; layer++) {
        const float* W = (layer == 0) ? W2 : (layer == 1) ? W3 : W4;
        const float* b = (layer == 0) ? b2 : (layer == 1) ? b3 : b4;
        #pragma unroll
        for (int j = 0; j < 32; j++) acc[j] = b[c0 + j];
        for (int k = 0; k < 256; k++) {
            float hv = h[k * 64 + r];
            const float* Wr = W + k * 256 + c0;
            #pragma unroll
            for (int j = 0; j < 32; j++) acc[j] = fmaf(hv, Wr[j], acc[j]);
        }
        __syncthreads();
        #pragma unroll
        for (int j = 0; j < 32; j++) h[(c0 + j) * 64 + r] = selu_f(acc[j]);
        __syncthreads();
    }

    // ---- layer 5 (256 -> 2): each group sums its own k-chunk ----
    float p0 = 0.f, p1 = 0.f;
    for (int kk = 0; kk < 32; kk++) {
        int k = c0 + kk;
        float hv = h[k * 64 + r];
        p0 = fmaf(hv, W5[k * 2 + 0], p0);
        p1 = fmaf(hv, W5[k * 2 + 1], p1);
    }
    __syncthreads();
    h[(0 * 8 + g) * 64 + r] = p0;
    h[(1 * 8 + g) * 64 + r] = p1;
    __syncthreads();
    if (t < 128) {
        int d  = t >> 6;
        int rr = t & 63;
        float sum = b5[d];
        #pragma unroll
        for (int gg = 0; gg < 8; gg++) sum += h[(d * 8 + gg) * 64 + rr];
        gen[(row0 + rr) * 2 + d] = sum;
    }
}

// ---------------------------------------------------------------------------
// Kernel B: two-pass softmin-distance energy, fp32 in/out.
// Block = 256 threads, 16 rows/block, 16 lanes per row (sub-wave groups ->
// shuffle-only reductions).  LDS tiles: 1024 pos + 1024 gen points (16 KB).
// ---------------------------------------------------------------------------
__global__ __launch_bounds__(256) void energy_kernel(
    const float* __restrict__ gen,
    const float* __restrict__ pos,
    float* __restrict__ out)
{
    __shared__ float4 sp[512];   // 1024 pos points
    __shared__ float4 sg[512];   // 1024 gen points

    const int t  = threadIdx.x;
    const int s  = t & 15;       // lane within row-group
    const int rl = t >> 4;       // 0..15 row within block
    const int i  = blockIdx.x * 16 + rl;

    const float2 q = ((const float2*)gen)[i];

    float minp = 3.4e38f, minn = 3.4e38f;

    // ---------------- pass 1: min d^2 ----------------
    for (int base = 0; base < N_PTS; base += 1024) {
        __syncthreads();
        #pragma unroll
        for (int u = 0; u < 2; u++) {
            int idx = u * 256 + t;
            sp[idx] = ((const float4*)pos)[base / 2 + idx];
            sg[idx] = ((const float4*)gen)[base / 2 + idx];
        }
        __syncthreads();
        #pragma unroll 4
        for (int u = 0; u < 32; u++) {
            int j = 2 * s + 32 * u;
            float4 pp = sp[j >> 1];
            float4 gg = sg[j >> 1];
            {
                float dx = q.x - pp.x, dy = q.y - pp.y;
                float d2 = fmaf(dx, dx, dy * dy);
                minp = fminf(minp, d2);
                dx = q.x - gg.x; dy = q.y - gg.y;
                d2 = fmaf(dx, dx, dy * dy);
                minn = (base + j == i) ? minn : fminf(minn, d2);
            }
            {
                float dx = q.x - pp.z, dy = q.y - pp.w;
                float d2 = fmaf(dx, dx, dy * dy);
                minp = fminf(minp, d2);
                dx = q.x - gg.z; dy = q.y - gg.w;
                d2 = fmaf(dx, dx, dy * dy);
                minn = (base + j + 1 == i) ? minn : fminf(minn, d2);
            }
        }
    }
    #pragma unroll
    for (int m = 1; m < 16; m <<= 1) {
        minp = fminf(minp, __shfl_xor(minp, m, 16));
        minn = fminf(minn, __shfl_xor(minn, m, 16));
    }
    const float dminp = sqrtf(minp);
    const float dminn = sqrtf(minn);
    const float invT  = 1.0f / TEMP_F;

    float sump = 0.f, sumn = 0.f;

    // ---------------- pass 2: sum exp((dmin-d)/T) ----------------
    for (int base = 0; base < N_PTS; base += 1024) {
        __syncthreads();
        #pragma unroll
        for (int u = 0; u < 2; u++) {
            int idx = u * 256 + t;
            sp[idx] = ((const float4*)pos)[base / 2 + idx];
            sg[idx] = ((const float4*)gen)[base / 2 + idx];
        }
        __syncthreads();
        #pragma unroll 4
        for (int u = 0; u < 32; u++) {
            int j = 2 * s + 32 * u;
            float4 pp = sp[j >> 1];
            float4 gg = sg[j >> 1];
            {
                float dx = q.x - pp.x, dy = q.y - pp.y;
                float d  = sqrtf(fmaf(dx, dx, dy * dy));
                sump += __expf((dminp - d) * invT);
                dx = q.x - gg.x; dy = q.y - gg.y;
                d  = sqrtf(fmaf(dx, dx, dy * dy));
                float term = __expf((dminn - d) * invT);
                sumn += (base + j == i) ? 0.f : term;
            }
            {
                float dx = q.x - pp.z, dy = q.y - pp.w;
                float d  = sqrtf(fmaf(dx, dx, dy * dy));
                sump += __expf((dminp - d) * invT);
                dx = q.x - gg.z; dy = q.y - gg.w;
                d  = sqrtf(fmaf(dx, dx, dy * dy));
                float term = __expf((dminn - d) * invT);
                sumn += (base + j + 1 == i) ? 0.f : term;
            }
        }
    }
    #pragma unroll
    for (int m = 1; m < 16; m <<= 1) {
        sump += __shfl_xor(sump, m, 16);
        sumn += __shfl_xor(sumn, m, 16);
    }

    if (s == 0) {
        float ep = dminp - TEMP_F * __logf(sump);   // -T*LSE(-d_pos/T)
        float en = -dminn + TEMP_F * __logf(sumn);  // +T*LSE(-d_neg/T)
        out[i] = ep + en;                           // fp32 output
    }
}

// ---------------------------------------------------------------------------
extern "C" void kernel_launch(void* const* d_in, const int* in_sizes, int n_in,
                              void* d_out, int out_size, void* d_ws, size_t ws_size,
                              hipStream_t stream) {
    const float* pos = (const float*)d_in[0];
    const float* z   = (const float*)d_in[1];
    const float* W1  = (const float*)d_in[2];
    const float* b1  = (const float*)d_in[3];
    const float* W2  = (const float*)d_in[4];
    const float* b2  = (const float*)d_in[5];
    const float* W3  = (const float*)d_in[6];
    const float* b3  = (const float*)d_in[7];
    const float* W4  = (const float*)d_in[8];
    const float* b4  = (const float*)d_in[9];
    const float* W5  = (const float*)d_in[10];
    const float* b5  = (const float*)d_in[11];

    float* gen = (float*)d_ws;                    // N_PTS x 2 fp32 scratch

    mlp_kernel<<<N_PTS / 64, 512, 0, stream>>>(z, W1, b1, W2, b2, W3, b3,
                                               W4, b4, W5, b5, gen);
    energy_kernel<<<N_PTS / 16, 256, 0, stream>>>(gen, pos, (float*)d_out);
}